// Round 2
// baseline (144.797 us; speedup 1.0000x reference)
//
#include <hip/hip_runtime.h>
#include <hip/hip_bf16.h>

#define NL  128   // layers (n)
#define DK  256   // d_in (k)
#define DO_ 256   // d_out (o)
#define MB  1024  // batch (m)

typedef __attribute__((ext_vector_type(4))) float f32x4;
typedef __attribute__((ext_vector_type(8))) short bf16x8;
typedef __attribute__((ext_vector_type(8))) unsigned short u16x8;

static __device__ __forceinline__ unsigned short f2bf(float f) {
  __hip_bfloat16 h = __float2bfloat16(f);
  return __builtin_bit_cast(unsigned short, h);
}

// ---------------------------------------------------------------------------
// Prep: W[n][k][o] fp32  ->  Wt[n][o][k] bf16  (transpose + convert, in d_ws)
// grid (16, 128): blockIdx.x = (ktile<<2)|otile quadrants of the 256x256 slice
// ---------------------------------------------------------------------------
__global__ __launch_bounds__(256) void wt_prep(const float* __restrict__ W,
                                               unsigned short* __restrict__ Wt) {
  const int n     = blockIdx.y;
  const int ktile = (blockIdx.x >> 2) * 64;
  const int otile = (blockIdx.x & 3) * 64;
  __shared__ float tile[64][65];  // +1 pad: conflict-free column reads
  const float* Wn = W + (size_t)n * DK * DO_;
  const int t  = threadIdx.x;
  const int lr = t >> 4;         // 0..15
  const int lc = (t & 15) * 4;   // 0..60
#pragma unroll
  for (int p = 0; p < 4; ++p) {
    const int k = p * 16 + lr;
    const float4 v = *(const float4*)(Wn + (size_t)(ktile + k) * DO_ + otile + lc);
    tile[k][lc + 0] = v.x; tile[k][lc + 1] = v.y;
    tile[k][lc + 2] = v.z; tile[k][lc + 3] = v.w;
  }
  __syncthreads();
  const int o  = t >> 2;  // 0..63
  const int kq = t & 3;   // 16 k each
  u16x8 w0, w1;
#pragma unroll
  for (int j = 0; j < 8; ++j) w0[j] = f2bf(tile[kq * 16 + j][o]);
#pragma unroll
  for (int j = 0; j < 8; ++j) w1[j] = f2bf(tile[kq * 16 + 8 + j][o]);
  unsigned short* dst = Wt + ((size_t)(n * DO_ + otile + o) * DK + ktile + kq * 16);
  *(u16x8*)(dst)     = w0;
  *(u16x8*)(dst + 8) = w1;
}

// ---------------------------------------------------------------------------
// Main: LDS-free, barrier-free. Block = (n, 64-row m-tile), 4 o-waves.
// Wave tile 64m x 64o. A-fragments straight from x (fp32 -> bf16 in-reg),
// B-fragments straight from Wt (bf16, k-contiguous, L2/L3-resident).
// In-block reuse (A shared by 4 waves) is absorbed by L1/L2.
// ---------------------------------------------------------------------------
__global__ __launch_bounds__(256, 3) void nlinear_mfma(
    const float* __restrict__ X, const unsigned short* __restrict__ Wt,
    const float* __restrict__ bias, float* __restrict__ out) {
  const int n     = blockIdx.y;
  const int mbase = blockIdx.x * 64;
  const int t     = threadIdx.x;
  const int wave  = t >> 6;      // o-wave 0..3
  const int lane  = t & 63;
  const int lrow  = lane & 15;
  const int lhi   = lane >> 4;   // 0..3

  // A: lane holds x[mbase + mi*16 + lrow][n][s*32 + lhi*8 .. +8]  (8 fp32 = 32B)
  const float* xb = X + ((size_t)(mbase + lrow) * NL + n) * DK + lhi * 8;
  // B: lane holds Wt[n][wave*64 + oj*16 + lrow][s*32 + lhi*8 .. +8] (8 bf16 = 16B)
  const unsigned short* wb =
      Wt + (size_t)(n * DO_ + wave * 64 + lrow) * DK + lhi * 8;

  f32x4 acc[4][4];
#pragma unroll
  for (int i = 0; i < 4; ++i)
#pragma unroll
    for (int j = 0; j < 4; ++j) acc[i][j] = (f32x4){0.f, 0.f, 0.f, 0.f};

#pragma unroll
  for (int s = 0; s < 8; ++s) {  // 8 K-slices of 32
    bf16x8 bfr[4];
#pragma unroll
    for (int oj = 0; oj < 4; ++oj)
      bfr[oj] = *(const bf16x8*)(wb + (size_t)(oj * 16) * DK + s * 32);
    bf16x8 af[4];
#pragma unroll
    for (int mi = 0; mi < 4; ++mi) {
      const float* ap = xb + (size_t)(mi * 16) * NL * DK + s * 32;
      const f32x4 a0 = *(const f32x4*)ap;
      const f32x4 a1 = *(const f32x4*)(ap + 4);
      u16x8 w;
#pragma unroll
      for (int e = 0; e < 4; ++e) { w[e] = f2bf(a0[e]); w[4 + e] = f2bf(a1[e]); }
      af[mi] = __builtin_bit_cast(bf16x8, w);
    }
#pragma unroll
    for (int oj = 0; oj < 4; ++oj)
#pragma unroll
      for (int mi = 0; mi < 4; ++mi)
        acc[mi][oj] =
            __builtin_amdgcn_mfma_f32_16x16x32_bf16(af[mi], bfr[oj], acc[mi][oj], 0, 0, 0);
  }

  // epilogue: C/D layout col=lane&15, row=(lane>>4)*4+reg  [m89-verified]
  float bv[4];
#pragma unroll
  for (int oj = 0; oj < 4; ++oj) bv[oj] = bias[n * DO_ + wave * 64 + oj * 16 + lrow];
#pragma unroll
  for (int mi = 0; mi < 4; ++mi)
#pragma unroll
    for (int oj = 0; oj < 4; ++oj)
#pragma unroll
      for (int r = 0; r < 4; ++r) {
        const int row = mbase + mi * 16 + lhi * 4 + r;
        const int col = wave * 64 + oj * 16 + lrow;
        out[((size_t)row * NL + n) * DO_ + col] = acc[mi][oj][r] + bv[oj];
      }
}

// ---------------------------------------------------------------------------
// Fallback (only if ws too small for Wt): plain fp32, correct but slow.
// ---------------------------------------------------------------------------
__global__ __launch_bounds__(256) void nlinear_naive(
    const float* __restrict__ X, const float* __restrict__ W,
    const float* __restrict__ B, float* __restrict__ out) {
  const int n = blockIdx.y;
  const int m = blockIdx.x;
  const int o = threadIdx.x;
  __shared__ float xs[DK];
  xs[o] = X[((size_t)m * NL + n) * DK + o];
  __syncthreads();
  const float* Wn = W + (size_t)n * DK * DO_;
  float s = B[n * DO_ + o];
  for (int k = 0; k < DK; ++k) s = fmaf(xs[k], Wn[(size_t)k * DO_ + o], s);
  out[((size_t)m * NL + n) * DO_ + o] = s;
}

extern "C" void kernel_launch(void* const* d_in, const int* in_sizes, int n_in,
                              void* d_out, int out_size, void* d_ws, size_t ws_size,
                              hipStream_t stream) {
  const float* x = (const float*)d_in[0];
  const float* w = (const float*)d_in[1];
  const float* b = (const float*)d_in[2];
  float* out     = (float*)d_out;
  const size_t wt_bytes = (size_t)NL * DK * DO_ * sizeof(unsigned short);
  if (ws_size >= wt_bytes) {
    unsigned short* wt = (unsigned short*)d_ws;
    wt_prep<<<dim3(16, NL), 256, 0, stream>>>(w, wt);
    nlinear_mfma<<<dim3(MB / 64, NL), 256, 0, stream>>>(x, wt, b, out);
  } else {
    nlinear_naive<<<dim3(MB, NL), 256, 0, stream>>>(x, w, b, out);
  }
}

// Round 3
// 96.373 us; speedup vs baseline: 1.5025x; 1.5025x over previous
//
#include <hip/hip_runtime.h>
#include <hip/hip_bf16.h>

#define NL  128   // layers (n)
#define DK  256   // d_in (k)
#define DO_ 256   // d_out (o)
#define MB  1024  // batch (m)

typedef __attribute__((ext_vector_type(4))) float f32x4;
typedef __attribute__((ext_vector_type(8))) short bf16x8;
typedef __attribute__((ext_vector_type(8))) unsigned short u16x8;

static __device__ __forceinline__ unsigned short f2bf(float f) {
  __hip_bfloat16 h = __float2bfloat16(f);
  return __builtin_bit_cast(unsigned short, h);
}

// ---------------------------------------------------------------------------
// Prep: W[n][k][o] fp32  ->  Wt[n][o][k] bf16  (transpose + convert, in d_ws)
// ---------------------------------------------------------------------------
__global__ __launch_bounds__(256) void wt_prep(const float* __restrict__ W,
                                               unsigned short* __restrict__ Wt) {
  const int n     = blockIdx.y;
  const int ktile = (blockIdx.x >> 2) * 64;
  const int otile = (blockIdx.x & 3) * 64;
  __shared__ float tile[64][65];  // +1 pad: conflict-free column reads
  const float* Wn = W + (size_t)n * DK * DO_;
  const int t  = threadIdx.x;
  const int lr = t >> 4;         // 0..15
  const int lc = (t & 15) * 4;   // 0..60
#pragma unroll
  for (int p = 0; p < 4; ++p) {
    const int k = p * 16 + lr;
    const float4 v = *(const float4*)(Wn + (size_t)(ktile + k) * DO_ + otile + lc);
    tile[k][lc + 0] = v.x; tile[k][lc + 1] = v.y;
    tile[k][lc + 2] = v.z; tile[k][lc + 3] = v.w;
  }
  __syncthreads();
  const int o  = t >> 2;  // 0..63
  const int kq = t & 3;   // 16 k each
  u16x8 w0, w1;
#pragma unroll
  for (int j = 0; j < 8; ++j) w0[j] = f2bf(tile[kq * 16 + j][o]);
#pragma unroll
  for (int j = 0; j < 8; ++j) w1[j] = f2bf(tile[kq * 16 + 8 + j][o]);
  unsigned short* dst = Wt + ((size_t)(n * DO_ + otile + o) * DK + ktile + kq * 16);
  *(u16x8*)(dst)     = w0;
  *(u16x8*)(dst + 8) = w1;
}

// ---------------------------------------------------------------------------
// Main: R1 geometry (block = (n, 64-m tile), 4 o-waves, wave = 64m x 64o),
// but single-barrier schedule: issue ALL x loads up front (16 dwordx4/thread),
// convert+write the whole 64x256 A-tile into swizzled LDS, ONE barrier, then
// all 128 MFMAs with B gathered straight from L2-resident Wt. HBM latency is
// paid once per block, not once per K-step.
// ---------------------------------------------------------------------------
__global__ __launch_bounds__(256, 3) void nlinear_mfma(
    const float* __restrict__ X, const unsigned short* __restrict__ Wt,
    const float* __restrict__ bias, float* __restrict__ out) {
  const int n     = blockIdx.y;
  const int mbase = blockIdx.x * 64;
  const int t     = threadIdx.x;
  const int wave  = t >> 6;      // o-wave 0..3
  const int lane  = t & 63;
  const int lrow  = lane & 15;
  const int lhi   = lane >> 4;   // 0..3

  __shared__ unsigned short Alds[4][64 * 64];  // [kk][row*64+k'], 128B rows, swizzled

  // staging map: thread owns (row = t>>2, 16-k quarter = t&3) in each K-section
  const int srow = t >> 2;
  const int skq  = t & 3;
  const float* xsrc = X + ((size_t)(mbase + srow) * NL + n) * DK + skq * 16;

  const unsigned short* Wn = Wt + (size_t)n * DO_ * DK;

  f32x4 acc[4][4];
#pragma unroll
  for (int i = 0; i < 4; ++i)
#pragma unroll
    for (int j = 0; j < 4; ++j) acc[i][j] = (f32x4){0.f, 0.f, 0.f, 0.f};

  // 1) issue ALL global loads (16 dwordx4 in flight; one HBM round-trip/block)
  f32x4 sv[16];
#pragma unroll
  for (int kk = 0; kk < 4; ++kk)
#pragma unroll
    for (int j = 0; j < 4; ++j)
      sv[kk * 4 + j] = *(const f32x4*)(xsrc + kk * 64 + j * 4);

  // 2) convert + write the whole tile (same verified XOR-swizzle as R1)
#pragma unroll
  for (int kk = 0; kk < 4; ++kk) {
    char* ab = (char*)Alds[kk];
#pragma unroll
    for (int j = 0; j < 2; ++j) {
      u16x8 w;
      const f32x4 a0 = sv[kk * 4 + 2 * j];
      const f32x4 a1 = sv[kk * 4 + 2 * j + 1];
#pragma unroll
      for (int e = 0; e < 4; ++e) { w[e] = f2bf(a0[e]); w[4 + e] = f2bf(a1[e]); }
      *(u16x8*)(ab + srow * 128 + ((((skq << 1) | j) ^ (srow & 7)) << 4)) = w;
    }
  }

  // 3) the only barrier in the kernel
  __syncthreads();

  // 4) all compute, no further syncs; B straight from L2-resident Wt
#pragma unroll
  for (int kk = 0; kk < 4; ++kk) {
    char* ab = (char*)Alds[kk];
#pragma unroll
    for (int ks = 0; ks < 2; ++ks) {
      bf16x8 bfr[4];
#pragma unroll
      for (int oj = 0; oj < 4; ++oj)
        bfr[oj] = *(const bf16x8*)(
            Wn + (size_t)(wave * 64 + oj * 16 + lrow) * DK + kk * 64 + ks * 32 + lhi * 8);
      bf16x8 af[4];
#pragma unroll
      for (int mi = 0; mi < 4; ++mi) {
        const int row  = mi * 16 + lrow;
        const int slot = (ks * 4 + lhi) ^ (row & 7);
        af[mi] = *(const bf16x8*)(ab + row * 128 + slot * 16);
      }
#pragma unroll
      for (int oj = 0; oj < 4; ++oj)
#pragma unroll
        for (int mi = 0; mi < 4; ++mi)
          acc[mi][oj] =
              __builtin_amdgcn_mfma_f32_16x16x32_bf16(af[mi], bfr[oj], acc[mi][oj], 0, 0, 0);
    }
  }

  // epilogue: C/D layout col=lane&15, row=(lane>>4)*4+reg  [m89-verified]
  float bv[4];
#pragma unroll
  for (int oj = 0; oj < 4; ++oj) bv[oj] = bias[n * DO_ + wave * 64 + oj * 16 + lrow];
#pragma unroll
  for (int mi = 0; mi < 4; ++mi)
#pragma unroll
    for (int oj = 0; oj < 4; ++oj)
#pragma unroll
      for (int r = 0; r < 4; ++r) {
        const int row = mbase + mi * 16 + lhi * 4 + r;
        const int col = wave * 64 + oj * 16 + lrow;
        out[((size_t)row * NL + n) * DO_ + col] = acc[mi][oj][r] + bv[oj];
      }
}

// ---------------------------------------------------------------------------
// Fallback (only if ws too small for Wt): plain fp32, correct but slow.
// ---------------------------------------------------------------------------
__global__ __launch_bounds__(256) void nlinear_naive(
    const float* __restrict__ X, const float* __restrict__ W,
    const float* __restrict__ B, float* __restrict__ out) {
  const int n = blockIdx.y;
  const int m = blockIdx.x;
  const int o = threadIdx.x;
  __shared__ float xs[DK];
  xs[o] = X[((size_t)m * NL + n) * DK + o];
  __syncthreads();
  const float* Wn = W + (size_t)n * DK * DO_;
  float s = B[n * DO_ + o];
  for (int k = 0; k < DK; ++k) s = fmaf(xs[k], Wn[(size_t)k * DO_ + o], s);
  out[((size_t)m * NL + n) * DO_ + o] = s;
}

extern "C" void kernel_launch(void* const* d_in, const int* in_sizes, int n_in,
                              void* d_out, int out_size, void* d_ws, size_t ws_size,
                              hipStream_t stream) {
  const float* x = (const float*)d_in[0];
  const float* w = (const float*)d_in[1];
  const float* b = (const float*)d_in[2];
  float* out     = (float*)d_out;
  const size_t wt_bytes = (size_t)NL * DK * DO_ * sizeof(unsigned short);
  if (ws_size >= wt_bytes) {
    unsigned short* wt = (unsigned short*)d_ws;
    wt_prep<<<dim3(16, NL), 256, 0, stream>>>(w, wt);
    nlinear_mfma<<<dim3(MB / 64, NL), 256, 0, stream>>>(x, wt, b, out);
  } else {
    nlinear_naive<<<dim3(MB, NL), 256, 0, stream>>>(x, w, b, out);
  }
}